// Round 1
// baseline (8464.468 us; speedup 1.0000x reference)
//
#include <hip/hip_runtime.h>
#include <hip/hip_bf16.h>
#include <stdint.h>

#define D 128
#define KTOT 384
#define BN_EPS 1e-5f

// ---------------------------------------------------------------------------
// GEMM1: z = X @ W1 + b1  with X assembled on the fly (concat + gathers),
// bf16 z store, and per-column sum/sumsq accumulation for BatchNorm.
// Tile: 128x128, BK=16, 256 threads (16x16), 8x8 micro-tile (strided cols/rows).
// MODE 0: edge MLP   rows=E, X=[h[src]+h[dst], e, u[graph_id[src]]]
// MODE 1: atom MLP   rows=N, X=[sum_h, sum_e, u[graph_id]]
// MODE 2: global MLP rows=G, X=[sum_h_g, sum_e_g, u]
// ---------------------------------------------------------------------------
template<int MODE>
__global__ __launch_bounds__(256)
void gemm1_kernel(const float* __restrict__ P0,
                  const float* __restrict__ P1,
                  const float* __restrict__ P2,
                  const int* __restrict__ src,
                  const int* __restrict__ dst,
                  const int* __restrict__ graph_id,
                  const float* __restrict__ W1,
                  const float* __restrict__ b1,
                  __hip_bfloat16* __restrict__ z,
                  float* __restrict__ stat_sum,
                  float* __restrict__ stat_sq,
                  int M)
{
    __shared__ float As[128][17];
    __shared__ float Bs[16][129];
    __shared__ int s_i0[128], s_i1[128], s_i2[128];
    __shared__ float s_sum[128], s_sq[128];

    const int tid = threadIdx.x;
    const int tx = tid & 15, ty = tid >> 4;
    const int row0 = blockIdx.x * 128;
    const int colblk = blockIdx.y * 128;

    if (tid < 128) {
        int r = row0 + tid;
        bool v = r < M;
        if (MODE == 0) {
            int s = v ? src[r] : 0;
            int d = v ? dst[r] : 0;
            s_i0[tid] = s; s_i1[tid] = d;
            s_i2[tid] = v ? graph_id[s] : 0;
        } else if (MODE == 1) {
            s_i2[tid] = v ? graph_id[r] : 0;
        }
        s_sum[tid] = 0.f; s_sq[tid] = 0.f;
    }
    __syncthreads();

    float acc[8][8];
#pragma unroll
    for (int i = 0; i < 8; i++)
#pragma unroll
        for (int j = 0; j < 8; j++) acc[i][j] = 0.f;

    const int kl = tid & 15;
    const int rbase = tid >> 4;

    for (int kt = 0; kt < KTOT; kt += 16) {
        // stage A (gather/concat fused)
#pragma unroll
        for (int p = 0; p < 8; ++p) {
            int r = rbase + p * 16;
            int grow = row0 + r;
            int gk = kt + kl;
            float v = 0.f;
            if (grow < M) {
                if (MODE == 0) {
                    if (gk < 128)      v = P0[(size_t)s_i0[r] * D + gk] + P0[(size_t)s_i1[r] * D + gk];
                    else if (gk < 256) v = P1[(size_t)grow * D + (gk - 128)];
                    else               v = P2[(size_t)s_i2[r] * D + (gk - 256)];
                } else if (MODE == 1) {
                    if (gk < 128)      v = P0[(size_t)grow * D + gk];
                    else if (gk < 256) v = P1[(size_t)grow * D + (gk - 128)];
                    else               v = P2[(size_t)s_i2[r] * D + (gk - 256)];
                } else {
                    if (gk < 128)      v = P0[(size_t)grow * D + gk];
                    else if (gk < 256) v = P1[(size_t)grow * D + (gk - 128)];
                    else               v = P2[(size_t)grow * D + (gk - 256)];
                }
            }
            As[r][kl] = v;
        }
        // stage B: W1 rows kt..kt+15, cols colblk..colblk+127 (ldb = 384)
        {
            int n = tid & 127;
            int kb = tid >> 7;
#pragma unroll
            for (int p = 0; p < 8; ++p) {
                int k = kb + p * 2;
                Bs[k][n] = W1[(size_t)(kt + k) * KTOT + colblk + n];
            }
        }
        __syncthreads();
#pragma unroll
        for (int kk = 0; kk < 16; ++kk) {
            float a[8], b[8];
#pragma unroll
            for (int i = 0; i < 8; i++) a[i] = As[ty + 16 * i][kk];
#pragma unroll
            for (int j = 0; j < 8; j++) b[j] = Bs[kk][tx + 16 * j];
#pragma unroll
            for (int i = 0; i < 8; i++)
#pragma unroll
                for (int j = 0; j < 8; j++) acc[i][j] += a[i] * b[j];
        }
        __syncthreads();
    }

    // epilogue: + b1, bf16 store, column stats
    float csum[8], csq[8];
#pragma unroll
    for (int j = 0; j < 8; j++) { csum[j] = 0.f; csq[j] = 0.f; }
#pragma unroll
    for (int i = 0; i < 8; i++) {
        int grow = row0 + ty + 16 * i;
        if (grow < M) {
#pragma unroll
            for (int j = 0; j < 8; j++) {
                int gcol = colblk + tx + 16 * j;
                float zv = acc[i][j] + b1[gcol];
                z[(size_t)grow * KTOT + gcol] = __float2bfloat16(zv);
                csum[j] += zv; csq[j] += zv * zv;
            }
        }
    }
#pragma unroll
    for (int j = 0; j < 8; j++) {
        atomicAdd(&s_sum[tx + 16 * j], csum[j]);
        atomicAdd(&s_sq[tx + 16 * j], csq[j]);
    }
    __syncthreads();
    if (tid < 128) {
        atomicAdd(&stat_sum[colblk + tid], s_sum[tid]);
        atomicAdd(&stat_sq[colblk + tid], s_sq[tid]);
    }
}

// ---------------------------------------------------------------------------
// BN finalize: scale = g1 * rsqrt(var+eps); shift = beta1 - mu*scale
// ---------------------------------------------------------------------------
__global__ void bn_finalize_kernel(const float* __restrict__ ssum,
                                   const float* __restrict__ ssq,
                                   const float* __restrict__ g1,
                                   const float* __restrict__ beta1,
                                   float invM,
                                   float* __restrict__ scale,
                                   float* __restrict__ shift)
{
    int j = threadIdx.x;
    if (j < KTOT) {
        float mu = ssum[j] * invM;
        float var = ssq[j] * invM - mu * mu;
        float sc = g1[j] * rsqrtf(var + BN_EPS);
        scale[j] = sc;
        shift[j] = beta1[j] - mu * sc;
    }
}

// ---------------------------------------------------------------------------
// GEMM2: out = relu(z*scale+shift) @ W2 + b2, optional fused atomic scatter.
// N=128 fixed. MODE 0: scatter sum_e[dst];  MODE 1: scatter sum_h_g[graph_id];
// MODE 2: no scatter.
// ---------------------------------------------------------------------------
template<int MODE>
__global__ __launch_bounds__(256)
void gemm2_kernel(const __hip_bfloat16* __restrict__ z,
                  const float* __restrict__ scale,
                  const float* __restrict__ shift,
                  const float* __restrict__ W2,
                  const float* __restrict__ b2,
                  const int* __restrict__ idx,   // dst (MODE0) / graph_id (MODE1)
                  float* __restrict__ out,
                  float* __restrict__ scat,
                  int M)
{
    __shared__ float As[128][17];
    __shared__ float Bs[16][129];
    __shared__ float s_scale[KTOT], s_shift[KTOT];
    __shared__ int s_idx[128];

    const int tid = threadIdx.x;
    const int tx = tid & 15, ty = tid >> 4;
    const int row0 = blockIdx.x * 128;

    for (int i = tid; i < KTOT; i += 256) { s_scale[i] = scale[i]; s_shift[i] = shift[i]; }
    if (MODE != 2 && tid < 128) {
        int r = row0 + tid;
        s_idx[tid] = (r < M) ? idx[r] : 0;
    }
    __syncthreads();

    float acc[8][8];
#pragma unroll
    for (int i = 0; i < 8; i++)
#pragma unroll
        for (int j = 0; j < 8; j++) acc[i][j] = 0.f;

    const int kl = tid & 15;
    const int rbase = tid >> 4;

    for (int kt = 0; kt < KTOT; kt += 16) {
        // stage A: BN+ReLU on the fly
#pragma unroll
        for (int p = 0; p < 8; ++p) {
            int r = rbase + p * 16;
            int grow = row0 + r;
            int gk = kt + kl;
            float v = 0.f;
            if (grow < M) {
                float zz = __bfloat162float(z[(size_t)grow * KTOT + gk]);
                zz = zz * s_scale[gk] + s_shift[gk];
                v = fmaxf(zz, 0.f);
            }
            As[r][kl] = v;
        }
        // stage B: W2 rows kt..kt+15, 128 cols (ldb = 128)
        {
            int n = tid & 127;
            int kb = tid >> 7;
#pragma unroll
            for (int p = 0; p < 8; ++p) {
                int k = kb + p * 2;
                Bs[k][n] = W2[(size_t)(kt + k) * D + n];
            }
        }
        __syncthreads();
#pragma unroll
        for (int kk = 0; kk < 16; ++kk) {
            float a[8], b[8];
#pragma unroll
            for (int i = 0; i < 8; i++) a[i] = As[ty + 16 * i][kk];
#pragma unroll
            for (int j = 0; j < 8; j++) b[j] = Bs[kk][tx + 16 * j];
#pragma unroll
            for (int i = 0; i < 8; i++)
#pragma unroll
                for (int j = 0; j < 8; j++) acc[i][j] += a[i] * b[j];
        }
        __syncthreads();
    }

#pragma unroll
    for (int i = 0; i < 8; i++) {
        int r = ty + 16 * i;
        int grow = row0 + r;
        if (grow < M) {
#pragma unroll
            for (int j = 0; j < 8; j++) {
                int gcol = tx + 16 * j;
                float v = acc[i][j] + b2[gcol];
                out[(size_t)grow * D + gcol] = v;
                if (MODE == 0 || MODE == 1) {
                    atomicAdd(&scat[(size_t)s_idx[r] * D + gcol], v);
                }
            }
        }
    }
}

// ---------------------------------------------------------------------------
// sum_h init: sum_h = h
// ---------------------------------------------------------------------------
__global__ void copy_f4_kernel(const float4* __restrict__ in, float4* __restrict__ out, int n4)
{
    int i = blockIdx.x * blockDim.x + threadIdx.x;
    if (i < n4) out[i] = in[i];
}

// sum_h[dst[e]] += h[src[e]]  (32 threads/edge, float4 reads, scalar atomics)
__global__ void scatter_h_kernel(const float* __restrict__ h,
                                 const int* __restrict__ src,
                                 const int* __restrict__ dst,
                                 float* __restrict__ sum_h, int E)
{
    int t = blockIdx.x * blockDim.x + threadIdx.x;
    int e = t >> 5;
    if (e >= E) return;
    int c = (t & 31) * 4;
    const float4 v = *(const float4*)(h + (size_t)src[e] * D + c);
    float* p = sum_h + (size_t)dst[e] * D + c;
    atomicAdd(p + 0, v.x); atomicAdd(p + 1, v.y);
    atomicAdd(p + 2, v.z); atomicAdd(p + 3, v.w);
}

// sum_e_g[graph_id[i]] += 0.5 * sum_e[i]
__global__ void sum_eg_kernel(const float* __restrict__ sum_e,
                              const int* __restrict__ graph_id,
                              float* __restrict__ sum_e_g, int N)
{
    int t = blockIdx.x * blockDim.x + threadIdx.x;
    int i = t >> 5;
    if (i >= N) return;
    int c = (t & 31) * 4;
    const float4 v = *(const float4*)(sum_e + (size_t)i * D + c);
    float* p = sum_e_g + (size_t)graph_id[i] * D + c;
    atomicAdd(p + 0, 0.5f * v.x); atomicAdd(p + 1, 0.5f * v.y);
    atomicAdd(p + 2, 0.5f * v.z); atomicAdd(p + 3, 0.5f * v.w);
}

// ---------------------------------------------------------------------------
extern "C" void kernel_launch(void* const* d_in, const int* in_sizes, int n_in,
                              void* d_out, int out_size, void* d_ws, size_t ws_size,
                              hipStream_t stream)
{
    const float* h  = (const float*)d_in[0];
    const float* e  = (const float*)d_in[1];
    const float* u  = (const float*)d_in[2];
    const int* src  = (const int*)d_in[3];
    const int* dst  = (const int*)d_in[4];
    const int* gid  = (const int*)d_in[5];

    const float* bW1 = (const float*)d_in[6];  const float* bb1 = (const float*)d_in[7];
    const float* bg1 = (const float*)d_in[8];  const float* bbe = (const float*)d_in[9];
    const float* bW2 = (const float*)d_in[10]; const float* bb2 = (const float*)d_in[11];
    const float* aW1 = (const float*)d_in[12]; const float* ab1 = (const float*)d_in[13];
    const float* ag1 = (const float*)d_in[14]; const float* abe = (const float*)d_in[15];
    const float* aW2 = (const float*)d_in[16]; const float* ab2 = (const float*)d_in[17];
    const float* gW1 = (const float*)d_in[18]; const float* gb1 = (const float*)d_in[19];
    const float* gg1 = (const float*)d_in[20]; const float* gbe = (const float*)d_in[21];
    const float* gW2 = (const float*)d_in[22]; const float* gb2 = (const float*)d_in[23];

    const int N = in_sizes[0] / D;
    const int E = in_sizes[1] / D;
    const int G = in_sizes[2] / D;

    float* out   = (float*)d_out;
    float* h_new = out;
    float* e_new = out + (size_t)N * D;
    float* u_new = out + (size_t)N * D + (size_t)E * D;

    // workspace carve-up
    char* ws = (char*)d_ws;
    __hip_bfloat16* z = (__hip_bfloat16*)ws;
    size_t off = ((size_t)E * KTOT * sizeof(__hip_bfloat16) + 255) & ~(size_t)255;
    float* sum_e  = (float*)(ws + off); off += ((size_t)N * D * 4 + 255) & ~(size_t)255;
    float* sum_h  = (float*)(ws + off); off += ((size_t)N * D * 4 + 255) & ~(size_t)255;
    float* sum_hg = (float*)(ws + off); off += ((size_t)G * D * 4 + 255) & ~(size_t)255;
    float* sum_eg = (float*)(ws + off); off += ((size_t)G * D * 4 + 255) & ~(size_t)255;
    float* st_sum = (float*)(ws + off); off += KTOT * 4;
    float* st_sq  = (float*)(ws + off); off += KTOT * 4;
    float* bn_sc  = (float*)(ws + off); off += KTOT * 4;
    float* bn_sh  = (float*)(ws + off); off += KTOT * 4;

    const dim3 blk(256);

    // zero accumulators
    hipMemsetAsync(sum_e,  0, (size_t)N * D * 4, stream);
    hipMemsetAsync(sum_hg, 0, (size_t)G * D * 4, stream);
    hipMemsetAsync(sum_eg, 0, (size_t)G * D * 4, stream);

    // sum_h = h ; sum_h += scatter(h[src] -> dst)
    copy_f4_kernel<<<(N * 32 + 255) / 256, blk, 0, stream>>>((const float4*)h, (float4*)sum_h, N * 32);
    scatter_h_kernel<<<(E * 32 + 255) / 256, blk, 0, stream>>>(h, src, dst, sum_h, E);

    // ---- edge MLP ----
    hipMemsetAsync(st_sum, 0, KTOT * 4, stream);
    hipMemsetAsync(st_sq,  0, KTOT * 4, stream);
    gemm1_kernel<0><<<dim3((E + 127) / 128, 3), blk, 0, stream>>>(
        h, e, u, src, dst, gid, bW1, bb1, z, st_sum, st_sq, E);
    bn_finalize_kernel<<<1, KTOT, 0, stream>>>(st_sum, st_sq, bg1, bbe, 1.0f / (float)E, bn_sc, bn_sh);
    gemm2_kernel<0><<<dim3((E + 127) / 128, 1), blk, 0, stream>>>(
        z, bn_sc, bn_sh, bW2, bb2, dst, e_new, sum_e, E);

    // ---- atom MLP ----
    hipMemsetAsync(st_sum, 0, KTOT * 4, stream);
    hipMemsetAsync(st_sq,  0, KTOT * 4, stream);
    gemm1_kernel<1><<<dim3((N + 127) / 128, 3), blk, 0, stream>>>(
        sum_h, sum_e, u, src, dst, gid, aW1, ab1, z, st_sum, st_sq, N);
    bn_finalize_kernel<<<1, KTOT, 0, stream>>>(st_sum, st_sq, ag1, abe, 1.0f / (float)N, bn_sc, bn_sh);
    gemm2_kernel<1><<<dim3((N + 127) / 128, 1), blk, 0, stream>>>(
        z, bn_sc, bn_sh, aW2, ab2, gid, h_new, sum_hg, N);

    // ---- global MLP ----
    sum_eg_kernel<<<(N * 32 + 255) / 256, blk, 0, stream>>>(sum_e, gid, sum_eg, N);
    hipMemsetAsync(st_sum, 0, KTOT * 4, stream);
    hipMemsetAsync(st_sq,  0, KTOT * 4, stream);
    gemm1_kernel<2><<<dim3((G + 127) / 128, 3), blk, 0, stream>>>(
        sum_hg, sum_eg, u, src, dst, gid, gW1, gb1, z, st_sum, st_sq, G);
    bn_finalize_kernel<<<1, KTOT, 0, stream>>>(st_sum, st_sq, gg1, gbe, 1.0f / (float)G, bn_sc, bn_sh);
    gemm2_kernel<2><<<dim3((G + 127) / 128, 1), blk, 0, stream>>>(
        z, bn_sc, bn_sh, gW2, gb2, nullptr, u_new, nullptr, G);
}

// Round 2
// 2825.486 us; speedup vs baseline: 2.9958x; 2.9958x over previous
//
#include <hip/hip_runtime.h>
#include <hip/hip_bf16.h>
#include <stdint.h>

#define D 128
#define KTOT 384
#define BN_EPS 1e-5f

typedef __attribute__((ext_vector_type(8))) short short8;
typedef __attribute__((ext_vector_type(4))) float floatx4;

__device__ __forceinline__ unsigned short f2bf(float f) {
    __hip_bfloat16 b = __float2bfloat16(f);
    return *reinterpret_cast<unsigned short*>(&b);
}
__device__ __forceinline__ float bf2f(unsigned short u) {
    unsigned int b = ((unsigned int)u) << 16;
    return __uint_as_float(b);
}

// ---------------------------------------------------------------------------
// Weight pre-pass: W [K][N] f32 row-major  ->  WT [N][K] bf16 (k-contiguous)
// ---------------------------------------------------------------------------
__global__ void convert_transpose_kernel(const float* __restrict__ W,
                                         unsigned short* __restrict__ WT,
                                         int K, int N)
{
    int idx = blockIdx.x * 256 + threadIdx.x;
    if (idx >= K * N) return;
    int k = idx / N, n = idx % N;
    WT[(size_t)n * K + k] = f2bf(W[idx]);
}

// ---------------------------------------------------------------------------
// GEMM1 (MFMA bf16): z = X @ W1 + b1, X assembled on the fly (concat+gather),
// bf16 z store via LDS-staged coalesced writes, fused BN column stats.
// Tile 128x128, BK=32, 256 threads = 4 waves (2x2), each wave 64x64 via
// 4x4 x mfma_f32_16x16x32_bf16.
// MODE 0: edge  X=[h[src]+h[dst], e, u[gid[src]]]
// MODE 1: atom  X=[sum_h, sum_e, u[gid]]
// MODE 2: glob  X=[sum_hg, sum_eg, u]
// ---------------------------------------------------------------------------
template<int MODE>
__global__ __launch_bounds__(256)
void gemm1_mfma_kernel(const float* __restrict__ P0,
                       const float* __restrict__ P1,
                       const float* __restrict__ P2,
                       const int* __restrict__ src,
                       const int* __restrict__ dst,
                       const int* __restrict__ graph_id,
                       const unsigned short* __restrict__ W1T, // [N=384][K=384] bf16
                       const float* __restrict__ b1,
                       unsigned short* __restrict__ z,          // [M][384] bf16
                       float* __restrict__ stat_sum,
                       float* __restrict__ stat_sq,
                       int M)
{
    // LDS layout (aliased):
    //   [0,10240)      As  short[128][40]   (K-loop)
    //   [10240,20480)  Bs  short[128][40]   (K-loop)
    //   [0,34816)      Zs  short[128][136]  (epilogue only)
    //   [34816,36352)  idx int[3][128]
    //   [36352,37376)  s_sum/s_sq float[128] each
    __shared__ __align__(16) char smem[37376];
    short (*As)[40] = (short(*)[40])smem;
    short (*Bs)[40] = (short(*)[40])(smem + 10240);
    short (*Zs)[136] = (short(*)[136])smem;
    int* s_i0 = (int*)(smem + 34816);
    int* s_i1 = s_i0 + 128;
    int* s_i2 = s_i1 + 128;
    float* s_sum = (float*)(smem + 36352);
    float* s_sq  = s_sum + 128;

    const int tid = threadIdx.x;
    const int row0 = blockIdx.x * 128;
    const int colblk = blockIdx.y * 128;

    if (tid < 128) {
        int r = row0 + tid;
        bool v = r < M;
        if (MODE == 0) {
            int s = v ? src[r] : 0;
            int d = v ? dst[r] : 0;
            s_i0[tid] = s; s_i1[tid] = d;
            s_i2[tid] = v ? graph_id[s] : 0;
        } else if (MODE == 1) {
            s_i2[tid] = v ? graph_id[r] : 0;
        }
        s_sum[tid] = 0.f; s_sq[tid] = 0.f;
    }
    __syncthreads();

    const int lane = tid & 63;
    const int wave = tid >> 6;
    const int wm = wave >> 1, wn = wave & 1;
    const int txl = lane & 15;
    const int quad = lane >> 4;
    const int kofs = quad * 8;

    const int r2 = tid >> 1;            // 0..127: A row / B col
    const int khalf = (tid & 1) * 16;   // 0 or 16

    floatx4 acc[4][4] = {};

    for (int kt = 0; kt < KTOT; kt += 32) {
        // ---- stage A: 16 f32 gathered -> bf16 -> LDS ----
        {
            int gk = kt + khalf;
            float v[16];
            int grow = row0 + r2;
            if (grow < M) {
                const float4* q0; const float4* q1 = nullptr;
                if (MODE == 0) {
                    if (gk < 128) {
                        q0 = (const float4*)(P0 + (size_t)s_i0[r2] * D + gk);
                        q1 = (const float4*)(P0 + (size_t)s_i1[r2] * D + gk);
                    } else if (gk < 256) {
                        q0 = (const float4*)(P1 + (size_t)grow * D + (gk - 128));
                    } else {
                        q0 = (const float4*)(P2 + (size_t)s_i2[r2] * D + (gk - 256));
                    }
                } else if (MODE == 1) {
                    if (gk < 128)      q0 = (const float4*)(P0 + (size_t)grow * D + gk);
                    else if (gk < 256) q0 = (const float4*)(P1 + (size_t)grow * D + (gk - 128));
                    else               q0 = (const float4*)(P2 + (size_t)s_i2[r2] * D + (gk - 256));
                } else {
                    if (gk < 128)      q0 = (const float4*)(P0 + (size_t)grow * D + gk);
                    else if (gk < 256) q0 = (const float4*)(P1 + (size_t)grow * D + (gk - 128));
                    else               q0 = (const float4*)(P2 + (size_t)grow * D + (gk - 256));
                }
#pragma unroll
                for (int q = 0; q < 4; q++) {
                    float4 a = q0[q];
                    if (MODE == 0 && q1) {
                        float4 b = q1[q];
                        a.x += b.x; a.y += b.y; a.z += b.z; a.w += b.w;
                    }
                    v[q * 4 + 0] = a.x; v[q * 4 + 1] = a.y;
                    v[q * 4 + 2] = a.z; v[q * 4 + 3] = a.w;
                }
            } else {
#pragma unroll
                for (int m = 0; m < 16; m++) v[m] = 0.f;
            }
            unsigned short t16[16];
#pragma unroll
            for (int m = 0; m < 16; m++) t16[m] = f2bf(v[m]);
            uint4* dp = (uint4*)&As[r2][khalf];
            dp[0] = *(const uint4*)&t16[0];
            dp[1] = *(const uint4*)&t16[8];
        }
        // ---- stage B: W1T bf16, 32B contiguous ----
        {
            const uint4* gp = (const uint4*)(W1T + (size_t)(colblk + r2) * KTOT + kt + khalf);
            uint4* dp = (uint4*)&Bs[r2][khalf];
            dp[0] = gp[0];
            dp[1] = gp[1];
        }
        __syncthreads();

        short8 af[4], bfr[4];
#pragma unroll
        for (int i = 0; i < 4; i++) af[i]  = *(const short8*)&As[wm * 64 + i * 16 + txl][kofs];
#pragma unroll
        for (int j = 0; j < 4; j++) bfr[j] = *(const short8*)&Bs[wn * 64 + j * 16 + txl][kofs];
#pragma unroll
        for (int i = 0; i < 4; i++)
#pragma unroll
            for (int j = 0; j < 4; j++)
                acc[i][j] = __builtin_amdgcn_mfma_f32_16x16x32_bf16(af[i], bfr[j], acc[i][j], 0, 0, 0);
        __syncthreads();
    }

    // ---- epilogue: +b1, bf16 into Zs, column stats ----
    float bias[4];
#pragma unroll
    for (int j = 0; j < 4; j++) bias[j] = b1[colblk + wn * 64 + j * 16 + txl];
    float csum[4] = {0.f, 0.f, 0.f, 0.f}, csq[4] = {0.f, 0.f, 0.f, 0.f};
#pragma unroll
    for (int i = 0; i < 4; i++) {
        int rl = wm * 64 + i * 16 + quad * 4;
#pragma unroll
        for (int j = 0; j < 4; j++) {
            int cl = wn * 64 + j * 16 + txl;
            floatx4 a = acc[i][j];
#pragma unroll
            for (int reg = 0; reg < 4; reg++) {
                float zv = a[reg] + bias[j];
                Zs[rl + reg][cl] = (short)f2bf(zv);
                if (row0 + rl + reg < M) { csum[j] += zv; csq[j] += zv * zv; }
            }
        }
    }
#pragma unroll
    for (int j = 0; j < 4; j++) {
        atomicAdd(&s_sum[wn * 64 + j * 16 + txl], csum[j]);
        atomicAdd(&s_sq[wn * 64 + j * 16 + txl], csq[j]);
    }
    __syncthreads();

    // coalesced copy Zs -> z
    {
        int grow = row0 + r2;
        if (grow < M) {
            const short* srcp = &Zs[r2][(tid & 1) * 64];
            unsigned short* dstp = z + (size_t)grow * KTOT + colblk + (tid & 1) * 64;
#pragma unroll
            for (int q = 0; q < 8; q++) {
                *(uint4*)(dstp + q * 8) = *(const uint4*)(srcp + q * 8);
            }
        }
    }
    if (tid < 128) {
        atomicAdd(&stat_sum[colblk + tid], s_sum[tid]);
        atomicAdd(&stat_sq[colblk + tid], s_sq[tid]);
    }
}

// ---------------------------------------------------------------------------
// BN finalize
// ---------------------------------------------------------------------------
__global__ void bn_finalize_kernel(const float* __restrict__ ssum,
                                   const float* __restrict__ ssq,
                                   const float* __restrict__ g1,
                                   const float* __restrict__ beta1,
                                   float invM,
                                   float* __restrict__ scale,
                                   float* __restrict__ shift)
{
    int j = threadIdx.x;
    if (j < KTOT) {
        float mu = ssum[j] * invM;
        float var = ssq[j] * invM - mu * mu;
        float sc = g1[j] * rsqrtf(var + BN_EPS);
        scale[j] = sc;
        shift[j] = beta1[j] - mu * sc;
    }
}

// ---------------------------------------------------------------------------
// GEMM2 (MFMA bf16): out = relu(z*scale+shift) @ W2 + b2, fused atomic scatter.
// MODE 0: scatter sum_e[dst]; MODE 1: scatter sum_hg[gid]; MODE 2: none.
// ---------------------------------------------------------------------------
template<int MODE>
__global__ __launch_bounds__(256)
void gemm2_mfma_kernel(const unsigned short* __restrict__ z,  // [M][384] bf16
                       const float* __restrict__ scale,
                       const float* __restrict__ shift,
                       const unsigned short* __restrict__ W2T, // [N=128][K=384] bf16
                       const float* __restrict__ b2,
                       const int* __restrict__ idx,
                       float* __restrict__ out,
                       float* __restrict__ scat,
                       int M)
{
    __shared__ __align__(16) short As[128][40];
    __shared__ __align__(16) short Bs[128][40];
    __shared__ float s_scale[KTOT], s_shift[KTOT];
    __shared__ int s_idx[128];

    const int tid = threadIdx.x;
    const int row0 = blockIdx.x * 128;

    for (int i = tid; i < KTOT; i += 256) { s_scale[i] = scale[i]; s_shift[i] = shift[i]; }
    if (MODE != 2 && tid < 128) {
        int r = row0 + tid;
        s_idx[tid] = (r < M) ? idx[r] : 0;
    }
    __syncthreads();

    const int lane = tid & 63;
    const int wave = tid >> 6;
    const int wm = wave >> 1, wn = wave & 1;
    const int txl = lane & 15;
    const int quad = lane >> 4;
    const int kofs = quad * 8;

    const int r2 = tid >> 1;
    const int khalf = (tid & 1) * 16;

    floatx4 acc[4][4] = {};

    for (int kt = 0; kt < KTOT; kt += 32) {
        // ---- stage A: z bf16 -> BN+ReLU -> bf16 LDS ----
        {
            int gk = kt + khalf;
            int grow = row0 + r2;
            unsigned short t16[16];
            if (grow < M) {
                const uint4* gp = (const uint4*)(z + (size_t)grow * KTOT + gk);
                uint4 w0 = gp[0], w1 = gp[1];
                const unsigned short* us = (const unsigned short*)&w0;
#pragma unroll
                for (int m = 0; m < 8; m++) {
                    float f = bf2f(us[m]);
                    f = fmaxf(f * s_scale[gk + m] + s_shift[gk + m], 0.f);
                    t16[m] = f2bf(f);
                }
                const unsigned short* us1 = (const unsigned short*)&w1;
#pragma unroll
                for (int m = 0; m < 8; m++) {
                    float f = bf2f(us1[m]);
                    f = fmaxf(f * s_scale[gk + 8 + m] + s_shift[gk + 8 + m], 0.f);
                    t16[8 + m] = f2bf(f);
                }
            } else {
#pragma unroll
                for (int m = 0; m < 16; m++) t16[m] = 0;
            }
            uint4* dp = (uint4*)&As[r2][khalf];
            dp[0] = *(const uint4*)&t16[0];
            dp[1] = *(const uint4*)&t16[8];
        }
        // ---- stage B ----
        {
            const uint4* gp = (const uint4*)(W2T + (size_t)r2 * KTOT + kt + khalf);
            uint4* dp = (uint4*)&Bs[r2][khalf];
            dp[0] = gp[0];
            dp[1] = gp[1];
        }
        __syncthreads();

        short8 af[4], bfr[4];
#pragma unroll
        for (int i = 0; i < 4; i++) af[i]  = *(const short8*)&As[wm * 64 + i * 16 + txl][kofs];
#pragma unroll
        for (int j = 0; j < 4; j++) bfr[j] = *(const short8*)&Bs[wn * 64 + j * 16 + txl][kofs];
#pragma unroll
        for (int i = 0; i < 4; i++)
#pragma unroll
            for (int j = 0; j < 4; j++)
                acc[i][j] = __builtin_amdgcn_mfma_f32_16x16x32_bf16(af[i], bfr[j], acc[i][j], 0, 0, 0);
        __syncthreads();
    }

    float bias[4];
#pragma unroll
    for (int j = 0; j < 4; j++) bias[j] = b2[wn * 64 + j * 16 + txl];
#pragma unroll
    for (int i = 0; i < 4; i++) {
#pragma unroll
        for (int reg = 0; reg < 4; reg++) {
            int rl = wm * 64 + i * 16 + quad * 4 + reg;
            int grow = row0 + rl;
            if (grow < M) {
#pragma unroll
                for (int j = 0; j < 4; j++) {
                    int c = wn * 64 + j * 16 + txl;
                    float v = acc[i][j][reg] + bias[j];
                    out[(size_t)grow * D + c] = v;
                    if (MODE == 0 || MODE == 1) {
                        atomicAdd(&scat[(size_t)s_idx[rl] * D + c], v);
                    }
                }
            }
        }
    }
}

// ---------------------------------------------------------------------------
__global__ void copy_f4_kernel(const float4* __restrict__ in, float4* __restrict__ out, int n4)
{
    int i = blockIdx.x * blockDim.x + threadIdx.x;
    if (i < n4) out[i] = in[i];
}

__global__ void scatter_h_kernel(const float* __restrict__ h,
                                 const int* __restrict__ src,
                                 const int* __restrict__ dst,
                                 float* __restrict__ sum_h, int E)
{
    int t = blockIdx.x * blockDim.x + threadIdx.x;
    int e = t >> 5;
    if (e >= E) return;
    int c = (t & 31) * 4;
    const float4 v = *(const float4*)(h + (size_t)src[e] * D + c);
    float* p = sum_h + (size_t)dst[e] * D + c;
    atomicAdd(p + 0, v.x); atomicAdd(p + 1, v.y);
    atomicAdd(p + 2, v.z); atomicAdd(p + 3, v.w);
}

__global__ void sum_eg_kernel(const float* __restrict__ sum_e,
                              const int* __restrict__ graph_id,
                              float* __restrict__ sum_e_g, int N)
{
    int t = blockIdx.x * blockDim.x + threadIdx.x;
    int i = t >> 5;
    if (i >= N) return;
    int c = (t & 31) * 4;
    const float4 v = *(const float4*)(sum_e + (size_t)i * D + c);
    float* p = sum_e_g + (size_t)graph_id[i] * D + c;
    atomicAdd(p + 0, 0.5f * v.x); atomicAdd(p + 1, 0.5f * v.y);
    atomicAdd(p + 2, 0.5f * v.z); atomicAdd(p + 3, 0.5f * v.w);
}

// ---------------------------------------------------------------------------
extern "C" void kernel_launch(void* const* d_in, const int* in_sizes, int n_in,
                              void* d_out, int out_size, void* d_ws, size_t ws_size,
                              hipStream_t stream)
{
    const float* h  = (const float*)d_in[0];
    const float* e  = (const float*)d_in[1];
    const float* u  = (const float*)d_in[2];
    const int* src  = (const int*)d_in[3];
    const int* dst  = (const int*)d_in[4];
    const int* gid  = (const int*)d_in[5];

    const float* bW1 = (const float*)d_in[6];  const float* bb1 = (const float*)d_in[7];
    const float* bg1 = (const float*)d_in[8];  const float* bbe = (const float*)d_in[9];
    const float* bW2 = (const float*)d_in[10]; const float* bb2 = (const float*)d_in[11];
    const float* aW1 = (const float*)d_in[12]; const float* ab1 = (const float*)d_in[13];
    const float* ag1 = (const float*)d_in[14]; const float* abe = (const float*)d_in[15];
    const float* aW2 = (const float*)d_in[16]; const float* ab2 = (const float*)d_in[17];
    const float* gW1 = (const float*)d_in[18]; const float* gb1 = (const float*)d_in[19];
    const float* gg1 = (const float*)d_in[20]; const float* gbe = (const float*)d_in[21];
    const float* gW2 = (const float*)d_in[22]; const float* gb2 = (const float*)d_in[23];

    const int N = in_sizes[0] / D;
    const int E = in_sizes[1] / D;
    const int G = in_sizes[2] / D;

    float* out   = (float*)d_out;
    float* h_new = out;
    float* e_new = out + (size_t)N * D;
    float* u_new = out + (size_t)N * D + (size_t)E * D;

    // workspace carve-up
    char* ws = (char*)d_ws;
    unsigned short* z = (unsigned short*)ws;
    size_t off = ((size_t)E * KTOT * sizeof(unsigned short) + 255) & ~(size_t)255;
    float* sum_e  = (float*)(ws + off); off += ((size_t)N * D * 4 + 255) & ~(size_t)255;
    float* sum_h  = (float*)(ws + off); off += ((size_t)N * D * 4 + 255) & ~(size_t)255;
    float* sum_hg = (float*)(ws + off); off += ((size_t)G * D * 4 + 255) & ~(size_t)255;
    float* sum_eg = (float*)(ws + off); off += ((size_t)G * D * 4 + 255) & ~(size_t)255;
    float* st_sum = (float*)(ws + off); off += KTOT * 4;
    float* st_sq  = (float*)(ws + off); off += KTOT * 4;
    float* bn_sc  = (float*)(ws + off); off += KTOT * 4;
    float* bn_sh  = (float*)(ws + off); off += KTOT * 4;
    off = (off + 255) & ~(size_t)255;
    unsigned short* w1t_b = (unsigned short*)(ws + off); off += (size_t)KTOT * KTOT * 2;
    unsigned short* w2t_b = (unsigned short*)(ws + off); off += (size_t)KTOT * D * 2;
    unsigned short* w1t_a = (unsigned short*)(ws + off); off += (size_t)KTOT * KTOT * 2;
    unsigned short* w2t_a = (unsigned short*)(ws + off); off += (size_t)KTOT * D * 2;
    unsigned short* w1t_g = (unsigned short*)(ws + off); off += (size_t)KTOT * KTOT * 2;
    unsigned short* w2t_g = (unsigned short*)(ws + off); off += (size_t)KTOT * D * 2;

    const dim3 blk(256);

    // weight pre-pass (bf16 transpose)
    {
        int n1 = KTOT * KTOT, n2 = KTOT * D;
        convert_transpose_kernel<<<(n1 + 255) / 256, blk, 0, stream>>>(bW1, w1t_b, KTOT, KTOT);
        convert_transpose_kernel<<<(n2 + 255) / 256, blk, 0, stream>>>(bW2, w2t_b, KTOT, D);
        convert_transpose_kernel<<<(n1 + 255) / 256, blk, 0, stream>>>(aW1, w1t_a, KTOT, KTOT);
        convert_transpose_kernel<<<(n2 + 255) / 256, blk, 0, stream>>>(aW2, w2t_a, KTOT, D);
        convert_transpose_kernel<<<(n1 + 255) / 256, blk, 0, stream>>>(gW1, w1t_g, KTOT, KTOT);
        convert_transpose_kernel<<<(n2 + 255) / 256, blk, 0, stream>>>(gW2, w2t_g, KTOT, D);
    }

    // zero accumulators
    hipMemsetAsync(sum_e,  0, (size_t)N * D * 4, stream);
    hipMemsetAsync(sum_hg, 0, (size_t)G * D * 4, stream);
    hipMemsetAsync(sum_eg, 0, (size_t)G * D * 4, stream);

    // sum_h = h + scatter(h[src] -> dst)
    copy_f4_kernel<<<(N * 32 + 255) / 256, blk, 0, stream>>>((const float4*)h, (float4*)sum_h, N * 32);
    scatter_h_kernel<<<(E * 32 + 255) / 256, blk, 0, stream>>>(h, src, dst, sum_h, E);

    // ---- edge MLP ----
    hipMemsetAsync(st_sum, 0, KTOT * 4, stream);
    hipMemsetAsync(st_sq,  0, KTOT * 4, stream);
    gemm1_mfma_kernel<0><<<dim3((E + 127) / 128, 3), blk, 0, stream>>>(
        h, e, u, src, dst, gid, w1t_b, bb1, z, st_sum, st_sq, E);
    bn_finalize_kernel<<<1, KTOT, 0, stream>>>(st_sum, st_sq, bg1, bbe, 1.0f / (float)E, bn_sc, bn_sh);
    gemm2_mfma_kernel<0><<<dim3((E + 127) / 128, 1), blk, 0, stream>>>(
        z, bn_sc, bn_sh, w2t_b, bb2, dst, e_new, sum_e, E);

    // ---- atom MLP ----
    hipMemsetAsync(st_sum, 0, KTOT * 4, stream);
    hipMemsetAsync(st_sq,  0, KTOT * 4, stream);
    gemm1_mfma_kernel<1><<<dim3((N + 127) / 128, 3), blk, 0, stream>>>(
        sum_h, sum_e, u, src, dst, gid, w1t_a, ab1, z, st_sum, st_sq, N);
    bn_finalize_kernel<<<1, KTOT, 0, stream>>>(st_sum, st_sq, ag1, abe, 1.0f / (float)N, bn_sc, bn_sh);
    gemm2_mfma_kernel<1><<<dim3((N + 127) / 128, 1), blk, 0, stream>>>(
        z, bn_sc, bn_sh, w2t_a, ab2, gid, h_new, sum_hg, N);

    // ---- global MLP ----
    sum_eg_kernel<<<(N * 32 + 255) / 256, blk, 0, stream>>>(sum_e, gid, sum_eg, N);
    hipMemsetAsync(st_sum, 0, KTOT * 4, stream);
    hipMemsetAsync(st_sq,  0, KTOT * 4, stream);
    gemm1_mfma_kernel<2><<<dim3((G + 127) / 128, 3), blk, 0, stream>>>(
        sum_hg, sum_eg, u, src, dst, gid, w1t_g, gb1, z, st_sum, st_sq, G);
    bn_finalize_kernel<<<1, KTOT, 0, stream>>>(st_sum, st_sq, gg1, gbe, 1.0f / (float)G, bn_sc, bn_sh);
    gemm2_mfma_kernel<2><<<dim3((G + 127) / 128, 1), blk, 0, stream>>>(
        z, bn_sc, bn_sh, w2t_g, gb2, nullptr, u_new, nullptr, G);
}